// Round 5
// baseline (489.743 us; speedup 1.0000x reference)
//
#include <hip/hip_runtime.h>
#include <hip/hip_bf16.h>
#include <math.h>

// Problem constants (fixed by the reference)
#define B_    2
#define N_    120000
#define S_    40000
#define M_    30000
#define V_    100000
#define H_    256
#define WD_   1024
#define HID_  128
#define NSC_  4
#define NCLS_ 20
#define BM_   60000    // B*M rows of the image branch
#define BS_   80000    // B*S sample rows
#define BN_   240000   // B*N point rows

#define SCALE_BLKS 3752          // ceil(60000/64)*4
#define OUT3D_BLKS 30000

typedef __attribute__((ext_vector_type(8))) short bfrag8;   // 8 bf16 (4 VGPRs) MFMA A/B frag
typedef __attribute__((ext_vector_type(4))) float facc4;    // 4 f32 MFMA C/D frag (native vec)
typedef __attribute__((ext_vector_type(4))) unsigned short usvec4;

__device__ __forceinline__ unsigned short f2bf(float f){
  unsigned u = __builtin_bit_cast(unsigned, f);
  u += 0x7fffu + ((u >> 16) & 1u);          // round-to-nearest-even
  return (unsigned short)(u >> 16);
}
__device__ __forceinline__ float bf2f(unsigned short s){
  return __builtin_bit_cast(float, ((unsigned)s) << 16);
}

// ---------------------------------------------------------------------------
// Front kernel: three independent jobs in disjoint block ranges.
//   [0, 30000)        img gather:  iap[row][h] = bf16(img[b][h][r][c])
//   [30000, 30938)    winner scatters (last-wins == max index)
//   [30938, 32228)    weight pre-transpose to bf16 [n][k]
__global__ __launch_bounds__(256) void k_front(
    const float* __restrict__ img, const int* __restrict__ ptsimg,
    unsigned short* __restrict__ iap,
    const int* __restrict__ p2i, const int* __restrict__ si,
    const int* __restrict__ ci,
    int* __restrict__ win_p, int* __restrict__ win_s, int* __restrict__ win_c,
    const float* __restrict__ lW, const float* __restrict__ f1W,
    const float* __restrict__ f2W, const float* __restrict__ c1W,
    const float* __restrict__ c2W,
    unsigned short* __restrict__ lwT, unsigned short* __restrict__ f1T,
    unsigned short* __restrict__ f2T, unsigned short* __restrict__ c1T,
    unsigned short* __restrict__ c2T){
  int bid = blockIdx.x;
  if (bid < 30000){                              // ---- img gather ----
    int t = bid * 256 + threadIdx.x;             // t = row*128 + h, exact
    int row = t >> 7, h = t & 127;
    int b = row / M_;
    int r = ptsimg[row * 2 + 0];
    int c = ptsimg[row * 2 + 1];
    iap[t] = f2bf(img[(((size_t)b * HID_ + h) * H_ + r) * WD_ + c]);
    return;
  }
  if (bid < 30938){                              // ---- winner scatters ----
    int t = (bid - 30000) * 256 + threadIdx.x;
    if (t < BM_) atomicMax(&win_p[(t / M_) * N_ + p2i[t]], t);
    if (t < BS_) atomicMax(&win_s[(t / S_) * N_ + si[t]], t);
    if (t < BN_) atomicMax(&win_c[ci[t]], t);
    return;
  }
  {                                              // ---- weight prep ----
    int t = (bid - 30938) * 256 + threadIdx.x;   // 330240 exact
    if (t < 65536){                              // leaner: 4 x [128][128]
      int i = t >> 14, r = t & 16383, n = r >> 7, k = r & 127;
      lwT[i * 16384 + n * 128 + k] = f2bf(lW[i * 16384 + k * 128 + n]);
    } else if (t < 196608){                      // fcs1: 4 x [128][256]
      int e = t - 65536;
      int i = e >> 15, r = e & 32767, n = r >> 8, k = r & 255;
      f1T[i * 32768 + n * 256 + k] = f2bf(f1W[i * 32768 + k * 128 + n]);
    } else if (t < 262144){                      // fcs2: 4 x [128][128]
      int e = t - 196608;
      int i = e >> 14, r = e & 16383, n = r >> 7, k = r & 127;
      f2T[i * 16384 + n * 128 + k] = f2bf(f2W[i * 16384 + k * 128 + n]);
    } else if (t < 327680){                      // cls_W1: [128][512]
      int e = t - 262144;
      int n = e >> 9, k = e & 511;
      c1T[n * 512 + k] = f2bf(c1W[k * 128 + n]);
    } else if (t < 330240){                      // cls_W2: [20][128]
      int e = t - 327680;
      int n = e >> 7, k = e & 127;
      c2T[n * 128 + k] = f2bf(c2W[k * NCLS_ + n]);
    }
    return;
  }
}

// ---------------------------------------------------------------------------
// Mega kernel: scales MLP (blocks [0, 3752)) + output_3d stream (blocks
// [3752, 33752)) — fully independent halves, co-resident so the pure-BW
// o3d stream fills slots the barrier-laced MLP leaves idle.
__global__ __launch_bounds__(256, 3) void k_mega(
    const float* __restrict__ samp, const unsigned short* __restrict__ iap,
    const int* __restrict__ win_p, const int* __restrict__ win_s,
    const int* __restrict__ win_c, const int* __restrict__ p2i,
    const int* __restrict__ ci, const float* __restrict__ imgf,
    const unsigned short* __restrict__ lwT, const float* __restrict__ lb,
    const unsigned short* __restrict__ f1T, const float* __restrict__ f1b,
    const unsigned short* __restrict__ f2T, const float* __restrict__ f2b,
    unsigned short* __restrict__ seg, float* __restrict__ o3d){
  __shared__ char lds[49152];
  if (blockIdx.x >= SCALE_BLKS){
    // ---- output_3d: o3d[j][i*128+c] = samp_i[win_s[j]] + iap[win_p[j]] ----
    int t = (blockIdx.x - SCALE_BLKS) * 256 + threadIdx.x;  // j*32 + q, exact
    int j = t >> 5, q = t & 31;
    int sj = win_s[j], pj = win_p[j];
    facc4 iv = {0.f, 0.f, 0.f, 0.f};
    if (pj >= 0){
      usvec4 u = __builtin_nontemporal_load((const usvec4*)(iap + (size_t)pj * HID_ + q * 4));
      iv.x = bf2f(u.x); iv.y = bf2f(u.y); iv.z = bf2f(u.z); iv.w = bf2f(u.w);
    }
    #pragma unroll
    for (int i = 0; i < NSC_; i++){
      facc4 v = iv;
      if (sj >= 0){
        facc4 s = __builtin_nontemporal_load((const facc4*)(samp + ((size_t)i * BS_ + sj) * HID_ + q * 4));
        v += s;
      }
      __builtin_nontemporal_store(v, (facc4*)(o3d + (size_t)j * (NSC_ * HID_) + i * HID_ + q * 4));
    }
    return;
  }
  // ---- scales MLP: i = bid&3, 64-row tile rb = bid>>2 ----
  char* actL = lds + 32768;
  const int i  = blockIdx.x & 3;
  const int rb = blockIdx.x >> 2;
  const int lane = threadIdx.x & 63, wv = threadIdx.x >> 6;
  const int rl = lane & 15, kg = lane >> 4;
  const int rowBase = rb * 64 + wv * 16;
  const int row = rowBase + rl;                 // this lane's A row
  const bool rv = row < BM_;
  const int lr = wv * 16 + rl;                  // block-local A row

  // ---- stage leaner W [128n][128k] (32KB) ----
  {
    const char* src = (const char*)(lwT + (size_t)i * 16384);
    for (int c = threadIdx.x; c < 2048; c += 256){
      int byte = c << 4; int n = byte >> 8;
      *(bfrag8*)(lds + (byte ^ ((n & 7) << 4))) = *(const bfrag8*)(src + byte);
    }
  }
  // A frags for leaner: sp = samp[i][win_s[g]] + iap[win_p[g]], g inline-chased
  bfrag8 afr[4];
  {
    int g = 0;
    if (rv){ int b = row >= M_; g = win_c[ci[b * N_ + p2i[row]]]; }
    int sj = rv ? win_s[g] : -1;
    int pj = rv ? win_p[g] : -1;
    const float* sp = samp + ((size_t)i * BS_ + (sj < 0 ? 0 : sj)) * HID_;
    const unsigned short* pp = iap + (size_t)(pj < 0 ? 0 : pj) * HID_;
    #pragma unroll
    for (int kc = 0; kc < 4; kc++){
      int k0 = kc * 32 + kg * 8;
      facc4 s0 = {0,0,0,0}, s1 = {0,0,0,0};
      if (sj >= 0){ s0 = *(const facc4*)(sp + k0); s1 = *(const facc4*)(sp + k0 + 4); }
      float g0=0,g1=0,g2=0,g3=0,g4=0,g5=0,g6=0,g7=0;
      if (pj >= 0){
        usvec4 u0 = *(const usvec4*)(pp + k0);
        usvec4 u1 = *(const usvec4*)(pp + k0 + 4);
        g0=bf2f(u0.x); g1=bf2f(u0.y); g2=bf2f(u0.z); g3=bf2f(u0.w);
        g4=bf2f(u1.x); g5=bf2f(u1.y); g6=bf2f(u1.z); g7=bf2f(u1.w);
      }
      bfrag8 a;
      a[0]=(short)f2bf(s0.x+g0); a[1]=(short)f2bf(s0.y+g1);
      a[2]=(short)f2bf(s0.z+g2); a[3]=(short)f2bf(s0.w+g3);
      a[4]=(short)f2bf(s1.x+g4); a[5]=(short)f2bf(s1.y+g5);
      a[6]=(short)f2bf(s1.z+g6); a[7]=(short)f2bf(s1.w+g7);
      afr[kc] = a;
    }
  }
  __syncthreads();
  // ---- Phase A: leaner MFMA ----
  facc4 accL[8];
  #pragma unroll
  for (int ct = 0; ct < 8; ct++) accL[ct] = (facc4){0.f,0.f,0.f,0.f};
  #pragma unroll
  for (int kc = 0; kc < 4; kc++){
    int k0 = kc * 32 + kg * 8;
    #pragma unroll
    for (int ct = 0; ct < 8; ct++){
      int col = ct * 16 + rl;
      int byte = (col << 8) + (k0 << 1);
      bfrag8 b = *(const bfrag8*)(lds + (byte ^ ((col & 7) << 4)));
      accL[ct] = __builtin_amdgcn_mfma_f32_16x16x32_bf16(afr[kc], b, accL[ct], 0, 0, 0);
    }
  }
  __syncthreads();                               // lW reads done
  // fl -> act LDS (bf16, relu); stage fcs1 K-half 0 (imgf part)
  {
    const float* bias = lb + i * HID_;
    #pragma unroll
    for (int ct = 0; ct < 8; ct++){
      int col = ct * 16 + rl;
      float bv = bias[col];
      #pragma unroll
      for (int r = 0; r < 4; r++){
        int ar = wv * 16 + kg * 4 + r;
        float v = accL[ct][r] + bv; v = v > 0.f ? v : 0.f;
        int byte = ar * 256 + col * 2;
        *(unsigned short*)(actL + (byte ^ ((ar & 7) << 4))) = f2bf(v);
      }
    }
    const char* src = (const char*)(f1T + (size_t)i * 32768);
    for (int c = threadIdx.x; c < 2048; c += 256){
      int n = c >> 4, off = (c & 15) << 4;
      *(bfrag8*)(lds + ((n * 256 + off) ^ ((n & 7) << 4))) =
          *(const bfrag8*)(src + (size_t)n * 512 + off);
    }
  }
  __syncthreads();
  // ---- Phase B1: fcs1, k in [0,128) — A = imgf (global) ----
  facc4 accF[8];
  #pragma unroll
  for (int ct = 0; ct < 8; ct++) accF[ct] = (facc4){0.f,0.f,0.f,0.f};
  {
    const float* a1 = imgf + ((size_t)i * BM_ + (rv ? row : 0)) * HID_;
    #pragma unroll
    for (int kc = 0; kc < 4; kc++){
      int kk = kc * 32 + kg * 8;
      bfrag8 a = (bfrag8){0,0,0,0,0,0,0,0};
      if (rv){
        facc4 s0 = *(const facc4*)(a1 + kk);
        facc4 s1 = *(const facc4*)(a1 + kk + 4);
        a[0]=(short)f2bf(s0.x); a[1]=(short)f2bf(s0.y); a[2]=(short)f2bf(s0.z); a[3]=(short)f2bf(s0.w);
        a[4]=(short)f2bf(s1.x); a[5]=(short)f2bf(s1.y); a[6]=(short)f2bf(s1.z); a[7]=(short)f2bf(s1.w);
      }
      #pragma unroll
      for (int ct = 0; ct < 8; ct++){
        int col = ct * 16 + rl;
        int byte = (col << 8) + (kk << 1);
        bfrag8 b = *(const bfrag8*)(lds + (byte ^ ((col & 7) << 4)));
        accF[ct] = __builtin_amdgcn_mfma_f32_16x16x32_bf16(a, b, accF[ct], 0, 0, 0);
      }
    }
  }
  __syncthreads();                               // f1-half0 reads done
  // stage fcs1 K-half 1 (fl part)
  {
    const char* src = (const char*)(f1T + (size_t)i * 32768) + 256;
    for (int c = threadIdx.x; c < 2048; c += 256){
      int n = c >> 4, off = (c & 15) << 4;
      *(bfrag8*)(lds + ((n * 256 + off) ^ ((n & 7) << 4))) =
          *(const bfrag8*)(src + (size_t)n * 512 + off);
    }
  }
  __syncthreads();
  // ---- Phase B2: fcs1, k in [128,256) — A = fl (act LDS) ----
  #pragma unroll
  for (int kc = 0; kc < 4; kc++){
    int kl = kc * 32 + kg * 8;
    int byteA = lr * 256 + kl * 2;
    bfrag8 a = *(const bfrag8*)(actL + (byteA ^ ((lr & 7) << 4)));
    #pragma unroll
    for (int ct = 0; ct < 8; ct++){
      int col = ct * 16 + rl;
      int byte = (col << 8) + (kl << 1);
      bfrag8 b = *(const bfrag8*)(lds + (byte ^ ((col & 7) << 4)));
      accF[ct] = __builtin_amdgcn_mfma_f32_16x16x32_bf16(a, b, accF[ct], 0, 0, 0);
    }
  }
  __syncthreads();                               // act(fl) + f1-half1 reads done
  // fc (+bias, kept f32 in accF) -> act LDS; stage fcs2 W
  {
    const float* bias = f1b + i * HID_;
    #pragma unroll
    for (int ct = 0; ct < 8; ct++){
      int col = ct * 16 + rl;
      float bv = bias[col];
      #pragma unroll
      for (int r = 0; r < 4; r++){
        int ar = wv * 16 + kg * 4 + r;
        float v = accF[ct][r] + bv;
        accF[ct][r] = v;
        int byte = ar * 256 + col * 2;
        *(unsigned short*)(actL + (byte ^ ((ar & 7) << 4))) = f2bf(v);
      }
    }
    const char* src = (const char*)(f2T + (size_t)i * 16384);
    for (int c = threadIdx.x; c < 2048; c += 256){
      int byte = c << 4; int n = byte >> 8;
      *(bfrag8*)(lds + (byte ^ ((n & 7) << 4))) = *(const bfrag8*)(src + byte);
    }
  }
  __syncthreads();
  // ---- Phase C: fcs2 + gate epilogue ----
  facc4 accT[8];
  #pragma unroll
  for (int ct = 0; ct < 8; ct++) accT[ct] = (facc4){0.f,0.f,0.f,0.f};
  #pragma unroll
  for (int kc = 0; kc < 4; kc++){
    int kk = kc * 32 + kg * 8;
    int byteA = lr * 256 + kk * 2;
    bfrag8 a = *(const bfrag8*)(actL + (byteA ^ ((lr & 7) << 4)));
    #pragma unroll
    for (int ct = 0; ct < 8; ct++){
      int col = ct * 16 + rl;
      int byte = (col << 8) + (kk << 1);
      bfrag8 b = *(const bfrag8*)(lds + (byte ^ ((col & 7) << 4)));
      accT[ct] = __builtin_amdgcn_mfma_f32_16x16x32_bf16(a, b, accT[ct], 0, 0, 0);
    }
  }
  {
    const float* bias2 = f2b + i * HID_;
    #pragma unroll
    for (int ct = 0; ct < 8; ct++){
      int col = ct * 16 + rl;
      float bv2 = bias2[col];
      #pragma unroll
      for (int r = 0; r < 4; r++){
        int orow = rowBase + kg * 4 + r;
        if (orow < BM_){
          float tv = accT[ct][r] + bv2;
          float fw = 1.f / (1.f + expf(-tv));
          float u = accF[ct][r] * fw;
          u = u > 0.f ? u : 0.f;
          seg[(size_t)orow * (NSC_ * HID_) + i * HID_ + col] = f2bf(u);
        }
      }
    }
  }
}

// Fused classifier: logits = relu(seg @ W1 + b1) @ W2 + b2.
// W1 staged as 4 x 32KB K-quarters; 48KB LDS, 3 blocks/CU.
__global__ __launch_bounds__(256, 3) void k_cls(const unsigned short* __restrict__ seg,
    const unsigned short* __restrict__ c1T, const float* __restrict__ c1b,
    const unsigned short* __restrict__ c2T, const float* __restrict__ c2b,
    float* __restrict__ logits){
  __shared__ char lds[49152];
  char* actL = lds + 32768;
  const int lane = threadIdx.x & 63, wv = threadIdx.x >> 6;
  const int rl = lane & 15, kg = lane >> 4;
  const int rowBase = blockIdx.x * 64 + wv * 16;
  const int row = rowBase + rl;
  const bool rv = row < BM_;
  const unsigned short* ar = seg + (size_t)(rv ? row : 0) * 512;
  facc4 acc[8];
  #pragma unroll
  for (int ct = 0; ct < 8; ct++) acc[ct] = (facc4){0.f,0.f,0.f,0.f};
  for (int ph = 0; ph < 4; ph++){
    if (ph) __syncthreads();
    for (int c = threadIdx.x; c < 2048; c += 256){
      int n = c >> 4, off = (c & 15) << 4;
      *(bfrag8*)(lds + ((n * 256 + off) ^ ((n & 7) << 4))) =
          *(const bfrag8*)((const char*)c1T + (size_t)n * 1024 + ph * 256 + off);
    }
    __syncthreads();
    #pragma unroll
    for (int kc = 0; kc < 4; kc++){
      int kl = kc * 32 + kg * 8;
      bfrag8 a = (bfrag8){0,0,0,0,0,0,0,0};
      if (rv) a = *(const bfrag8*)(ar + ph * 128 + kl);
      #pragma unroll
      for (int ct = 0; ct < 8; ct++){
        int col = ct * 16 + rl;
        int byte = (col << 8) + (kl << 1);
        bfrag8 b = *(const bfrag8*)(lds + (byte ^ ((col & 7) << 4)));
        acc[ct] = __builtin_amdgcn_mfma_f32_16x16x32_bf16(a, b, acc[ct], 0, 0, 0);
      }
    }
  }
  __syncthreads();
  // relu(hid) -> act LDS; stage W2 bf16 [20][128] (5120B at lds+0)
  #pragma unroll
  for (int ct = 0; ct < 8; ct++){
    int col = ct * 16 + rl;
    float bv = c1b[col];
    #pragma unroll
    for (int r = 0; r < 4; r++){
      int arr = wv * 16 + kg * 4 + r;
      float v = acc[ct][r] + bv; v = v > 0.f ? v : 0.f;
      int byte = arr * 256 + col * 2;
      *(unsigned short*)(actL + (byte ^ ((arr & 7) << 4))) = f2bf(v);
    }
  }
  for (int c = threadIdx.x; c < 320; c += 256)
    *(bfrag8*)(lds + (c << 4)) = *(const bfrag8*)((const char*)c2T + (c << 4));
  __syncthreads();
  // dot: thread -> (local row = t>>2, n-range = (t&3)*5 .. +5)
  {
    int t = threadIdx.x;
    int lrd = t >> 2, n0 = (t & 3) * 5;
    int orow = blockIdx.x * 64 + lrd;
    if (orow < BM_){
      float accD[5];
      #pragma unroll
      for (int q = 0; q < 5; q++) accD[q] = c2b[n0 + q];
      #pragma unroll
      for (int k8 = 0; k8 < 16; k8++){
        int byteA = lrd * 256 + (k8 << 4);
        bfrag8 hv = *(const bfrag8*)(actL + (byteA ^ ((lrd & 7) << 4)));
        #pragma unroll
        for (int q = 0; q < 5; q++){
          bfrag8 w8 = *(const bfrag8*)(lds + (n0 + q) * 256 + (k8 << 4));
          #pragma unroll
          for (int e = 0; e < 8; e++)
            accD[q] += bf2f((unsigned short)hv[e]) * bf2f((unsigned short)w8[e]);
        }
      }
      #pragma unroll
      for (int q = 0; q < 5; q++)
        logits[(size_t)orow * NCLS_ + n0 + q] = accD[q];
    }
  }
}

// ---------------------------------------------------------------------------
extern "C" void kernel_launch(void* const* d_in, const int* in_sizes, int n_in,
                              void* d_out, int out_size, void* d_ws, size_t ws_size,
                              hipStream_t stream){
  const float* samp = (const float*)d_in[1];   // pts_sample_feat (pts_feat_layers is dead)
  const float* img  = (const float*)d_in[2];
  const float* imgf = (const float*)d_in[3];
  const float* lW   = (const float*)d_in[4];
  const float* lb   = (const float*)d_in[5];
  const float* f1W  = (const float*)d_in[6];
  const float* f1b  = (const float*)d_in[7];
  const float* f2W  = (const float*)d_in[8];
  const float* f2b  = (const float*)d_in[9];
  const float* c1W  = (const float*)d_in[10];
  const float* c1b  = (const float*)d_in[11];
  const float* c2W  = (const float*)d_in[12];
  const float* c2b  = (const float*)d_in[13];
  const int* ptsimg = (const int*)d_in[14];
  const int* p2i    = (const int*)d_in[15];
  const int* si     = (const int*)d_in[16];
  const int* ci     = (const int*)d_in[17];

  char* ws = (char*)d_ws;
  int*   win_p = (int*)(ws + 0);                       //   960,000 B
  int*   win_s = (int*)(ws + 960000);                  //   960,000 B
  int*   win_c = (int*)(ws + 1920000);                 //   400,000 B
  unsigned short* iap = (unsigned short*)(ws + 2320128);    // 15,360,000 B
  unsigned short* seg = (unsigned short*)(ws + 17680384);   // 61,440,000 B
  unsigned short* lwT = (unsigned short*)(ws + 79120512);   // 131,072 B
  unsigned short* f1T = lwT + 65536;                        // 262,144 B
  unsigned short* f2T = f1T + 131072;                       // 131,072 B
  unsigned short* c1T = f2T + 65536;                        // 131,072 B
  unsigned short* c2T = c1T + 65536;                        //   5,120 B

  float* logits = (float*)d_out;
  float* o3d    = (float*)d_out + (size_t)BM_ * NCLS_;

  (void)hipMemsetAsync(ws, 0xFF, 2320000, stream);     // win_* = -1
  k_front<<<32228, 256, 0, stream>>>(img, ptsimg, iap, p2i, si, ci,
                                     win_p, win_s, win_c,
                                     lW, f1W, f2W, c1W, c2W,
                                     lwT, f1T, f2T, c1T, c2T);
  k_mega <<<SCALE_BLKS + OUT3D_BLKS, 256, 0, stream>>>(samp, iap,
                                     win_p, win_s, win_c, p2i, ci, imgf,
                                     lwT, lb, f1T, f1b, f2T, f2b, seg, o3d);
  k_cls  <<<938, 256, 0, stream>>>(seg, c1T, c1b, c2T, c2b, logits);
}

// Round 6
// 459.904 us; speedup vs baseline: 1.0649x; 1.0649x over previous
//
#include <hip/hip_runtime.h>
#include <hip/hip_bf16.h>
#include <math.h>

// Problem constants (fixed by the reference)
#define B_    2
#define N_    120000
#define S_    40000
#define M_    30000
#define V_    100000
#define H_    256
#define WD_   1024
#define HID_  128
#define NSC_  4
#define NCLS_ 20
#define BM_   60000    // B*M rows of the image branch
#define BS_   80000    // B*S sample rows
#define BN_   240000   // B*N point rows

typedef __attribute__((ext_vector_type(8))) short bfrag8;   // 8 bf16 (4 VGPRs) MFMA A/B frag
typedef __attribute__((ext_vector_type(4))) float facc4;    // 4 f32 MFMA C/D frag (native vec)
typedef __attribute__((ext_vector_type(4))) unsigned short usvec4;

__device__ __forceinline__ unsigned short f2bf(float f){
  unsigned u = __builtin_bit_cast(unsigned, f);
  u += 0x7fffu + ((u >> 16) & 1u);          // round-to-nearest-even
  return (unsigned short)(u >> 16);
}
__device__ __forceinline__ float bf2f(unsigned short s){
  return __builtin_bit_cast(float, ((unsigned)s) << 16);
}

// ---------------------------------------------------------------------------
// Front kernel: three independent jobs in disjoint block ranges (no LDS).
//   [0, 938)       winner scatters (last-wins == max index)
//   [938, 2228)    weight pre-transpose to bf16 [n][k]
//   [2228, 9728)   img gather: iap[row][h] = bf16(img[b][h][r][c]), 4 h / thread
__global__ __launch_bounds__(256) void k_front(
    const float* __restrict__ img, const int* __restrict__ ptsimg,
    unsigned short* __restrict__ iap,
    const int* __restrict__ p2i, const int* __restrict__ si,
    const int* __restrict__ ci,
    int* __restrict__ win_p, int* __restrict__ win_s, int* __restrict__ win_c,
    const float* __restrict__ lW, const float* __restrict__ f1W,
    const float* __restrict__ f2W, const float* __restrict__ c1W,
    const float* __restrict__ c2W,
    unsigned short* __restrict__ lwT, unsigned short* __restrict__ f1T,
    unsigned short* __restrict__ f2T, unsigned short* __restrict__ c1T,
    unsigned short* __restrict__ c2T){
  int bid = blockIdx.x;
  if (bid < 938){                                // ---- winner scatters ----
    int t = bid * 256 + threadIdx.x;
    if (t < BM_) atomicMax(&win_p[(t / M_) * N_ + p2i[t]], t);
    if (t < BS_) atomicMax(&win_s[(t / S_) * N_ + si[t]], t);
    if (t < BN_) atomicMax(&win_c[ci[t]], t);
    return;
  }
  if (bid < 2228){                               // ---- weight prep ----
    int t = (bid - 938) * 256 + threadIdx.x;     // 330240 exact
    if (t < 65536){                              // leaner: 4 x [128][128]
      int i = t >> 14, r = t & 16383, n = r >> 7, k = r & 127;
      lwT[i * 16384 + n * 128 + k] = f2bf(lW[i * 16384 + k * 128 + n]);
    } else if (t < 196608){                      // fcs1: 4 x [128][256]
      int e = t - 65536;
      int i = e >> 15, r = e & 32767, n = r >> 8, k = r & 255;
      f1T[i * 32768 + n * 256 + k] = f2bf(f1W[i * 32768 + k * 128 + n]);
    } else if (t < 262144){                      // fcs2: 4 x [128][128]
      int e = t - 196608;
      int i = e >> 14, r = e & 16383, n = r >> 7, k = r & 127;
      f2T[i * 16384 + n * 128 + k] = f2bf(f2W[i * 16384 + k * 128 + n]);
    } else if (t < 327680){                      // cls_W1: [128][512]
      int e = t - 262144;
      int n = e >> 9, k = e & 511;
      c1T[n * 512 + k] = f2bf(c1W[k * 128 + n]);
    } else if (t < 330240){                      // cls_W2: [20][128]
      int e = t - 327680;
      int n = e >> 7, k = e & 127;
      c2T[n * 128 + k] = f2bf(c2W[k * NCLS_ + n]);
    }
    return;
  }
  {                                              // ---- img gather ----
    int t = (bid - 2228) * 256 + threadIdx.x;    // t = row*32 + g, exact
    int row = t >> 5, h4 = (t & 31) * 4;
    int b = row / M_;
    int r = ptsimg[row * 2 + 0];
    int c = ptsimg[row * 2 + 1];
    const float* base = img + (((size_t)b * HID_ + h4) * H_ + r) * WD_ + c;
    const size_t st = (size_t)H_ * WD_;          // 1 h-plane = 262144 floats
    float v0 = base[0], v1 = base[st], v2 = base[2 * st], v3 = base[3 * st];
    usvec4 o = {f2bf(v0), f2bf(v1), f2bf(v2), f2bf(v3)};
    *(usvec4*)(iap + (size_t)row * HID_ + h4) = o;
    return;
  }
}

// ---------------------------------------------------------------------------
// output_3d stream: o3d[j][i*128+c] = samp_i[win_s[j]] + iap[win_p[j]].
// Zero-LDS, high occupancy (gather-latency needs waves). Plain loads (L3
// dedupes the ~2.8x row re-reads), NT stores (pure output stream).
__global__ __launch_bounds__(256) void k_o3d(const float* __restrict__ samp,
    const int* __restrict__ win_s, const int* __restrict__ win_p,
    const unsigned short* __restrict__ iap, float* __restrict__ o3d){
  int t = blockIdx.x * 256 + threadIdx.x;       // t = j*32 + q, exact grid
  int j = t >> 5, q = t & 31;
  int sj = win_s[j], pj = win_p[j];
  facc4 iv = {0.f, 0.f, 0.f, 0.f};
  if (pj >= 0){
    usvec4 u = *(const usvec4*)(iap + (size_t)pj * HID_ + q * 4);
    iv.x = bf2f(u.x); iv.y = bf2f(u.y); iv.z = bf2f(u.z); iv.w = bf2f(u.w);
  }
  #pragma unroll
  for (int i = 0; i < NSC_; i++){
    facc4 v = iv;
    if (sj >= 0){
      facc4 s = *(const facc4*)(samp + ((size_t)i * BS_ + sj) * HID_ + q * 4);
      v += s;
    }
    __builtin_nontemporal_store(v, (facc4*)(o3d + (size_t)j * (NSC_ * HID_) + i * HID_ + q * 4));
  }
}

// ---------------------------------------------------------------------------
// Merged per-scale MLP over ALL 4 scales (independent): i = blockIdx.x & 3.
// seg[:, i*128:(i+1)*128] = relu(fc * sigmoid(fc @ W2 + b2)),
//   fc = [imgf_i | relu(spG @ Wl + bl)] @ W1 + b1
// Block = 256 thr (4 waves), 64 rows. LDS 48KB: 32KB weight buf (fcs1 staged
// as two K-halves at the concat boundary) + 16KB act buf. 3 blocks/CU.
__global__ __launch_bounds__(256, 3) void k_scales(
    const float* __restrict__ samp, const unsigned short* __restrict__ iap,
    const int* __restrict__ win_p, const int* __restrict__ win_s,
    const int* __restrict__ win_c, const int* __restrict__ p2i,
    const int* __restrict__ ci, const float* __restrict__ imgf,
    const unsigned short* __restrict__ lwT, const float* __restrict__ lb,
    const unsigned short* __restrict__ f1T, const float* __restrict__ f1b,
    const unsigned short* __restrict__ f2T, const float* __restrict__ f2b,
    unsigned short* __restrict__ seg){
  __shared__ char lds[49152];
  char* actL = lds + 32768;
  const int i  = blockIdx.x & 3;
  const int rb = blockIdx.x >> 2;
  const int lane = threadIdx.x & 63, wv = threadIdx.x >> 6;
  const int rl = lane & 15, kg = lane >> 4;
  const int rowBase = rb * 64 + wv * 16;
  const int row = rowBase + rl;                 // this lane's A row
  const bool rv = row < BM_;
  const int lr = wv * 16 + rl;                  // block-local A row

  // ---- stage leaner W [128n][128k] (32KB) ----
  {
    const char* src = (const char*)(lwT + (size_t)i * 16384);
    for (int c = threadIdx.x; c < 2048; c += 256){
      int byte = c << 4; int n = byte >> 8;
      *(bfrag8*)(lds + (byte ^ ((n & 7) << 4))) = *(const bfrag8*)(src + byte);
    }
  }
  // A frags for leaner: sp = samp[i][win_s[g]] + iap[win_p[g]], g inline-chased
  bfrag8 afr[4];
  {
    int g = 0;
    if (rv){ int b = row >= M_; g = win_c[ci[b * N_ + p2i[row]]]; }
    int sj = rv ? win_s[g] : -1;
    int pj = rv ? win_p[g] : -1;
    const float* sp = samp + ((size_t)i * BS_ + (sj < 0 ? 0 : sj)) * HID_;
    const unsigned short* pp = iap + (size_t)(pj < 0 ? 0 : pj) * HID_;
    #pragma unroll
    for (int kc = 0; kc < 4; kc++){
      int k0 = kc * 32 + kg * 8;
      facc4 s0 = {0,0,0,0}, s1 = {0,0,0,0};
      if (sj >= 0){ s0 = *(const facc4*)(sp + k0); s1 = *(const facc4*)(sp + k0 + 4); }
      float g0=0,g1=0,g2=0,g3=0,g4=0,g5=0,g6=0,g7=0;
      if (pj >= 0){
        usvec4 u0 = *(const usvec4*)(pp + k0);
        usvec4 u1 = *(const usvec4*)(pp + k0 + 4);
        g0=bf2f(u0.x); g1=bf2f(u0.y); g2=bf2f(u0.z); g3=bf2f(u0.w);
        g4=bf2f(u1.x); g5=bf2f(u1.y); g6=bf2f(u1.z); g7=bf2f(u1.w);
      }
      bfrag8 a;
      a[0]=(short)f2bf(s0.x+g0); a[1]=(short)f2bf(s0.y+g1);
      a[2]=(short)f2bf(s0.z+g2); a[3]=(short)f2bf(s0.w+g3);
      a[4]=(short)f2bf(s1.x+g4); a[5]=(short)f2bf(s1.y+g5);
      a[6]=(short)f2bf(s1.z+g6); a[7]=(short)f2bf(s1.w+g7);
      afr[kc] = a;
    }
  }
  __syncthreads();
  // ---- Phase A: leaner MFMA ----
  facc4 accL[8];
  #pragma unroll
  for (int ct = 0; ct < 8; ct++) accL[ct] = (facc4){0.f,0.f,0.f,0.f};
  #pragma unroll
  for (int kc = 0; kc < 4; kc++){
    int k0 = kc * 32 + kg * 8;
    #pragma unroll
    for (int ct = 0; ct < 8; ct++){
      int col = ct * 16 + rl;
      int byte = (col << 8) + (k0 << 1);
      bfrag8 b = *(const bfrag8*)(lds + (byte ^ ((col & 7) << 4)));
      accL[ct] = __builtin_amdgcn_mfma_f32_16x16x32_bf16(afr[kc], b, accL[ct], 0, 0, 0);
    }
  }
  __syncthreads();                               // lW reads done
  // fl -> act LDS (bf16, relu); stage fcs1 K-half 0 (imgf part)
  {
    const float* bias = lb + i * HID_;
    #pragma unroll
    for (int ct = 0; ct < 8; ct++){
      int col = ct * 16 + rl;
      float bv = bias[col];
      #pragma unroll
      for (int r = 0; r < 4; r++){
        int ar = wv * 16 + kg * 4 + r;
        float v = accL[ct][r] + bv; v = v > 0.f ? v : 0.f;
        int byte = ar * 256 + col * 2;
        *(unsigned short*)(actL + (byte ^ ((ar & 7) << 4))) = f2bf(v);
      }
    }
    const char* src = (const char*)(f1T + (size_t)i * 32768);
    for (int c = threadIdx.x; c < 2048; c += 256){
      int n = c >> 4, off = (c & 15) << 4;
      *(bfrag8*)(lds + ((n * 256 + off) ^ ((n & 7) << 4))) =
          *(const bfrag8*)(src + (size_t)n * 512 + off);
    }
  }
  __syncthreads();
  // ---- Phase B1: fcs1, k in [0,128) — A = imgf (global) ----
  facc4 accF[8];
  #pragma unroll
  for (int ct = 0; ct < 8; ct++) accF[ct] = (facc4){0.f,0.f,0.f,0.f};
  {
    const float* a1 = imgf + ((size_t)i * BM_ + (rv ? row : 0)) * HID_;
    #pragma unroll
    for (int kc = 0; kc < 4; kc++){
      int kk = kc * 32 + kg * 8;
      bfrag8 a = (bfrag8){0,0,0,0,0,0,0,0};
      if (rv){
        facc4 s0 = *(const facc4*)(a1 + kk);
        facc4 s1 = *(const facc4*)(a1 + kk + 4);
        a[0]=(short)f2bf(s0.x); a[1]=(short)f2bf(s0.y); a[2]=(short)f2bf(s0.z); a[3]=(short)f2bf(s0.w);
        a[4]=(short)f2bf(s1.x); a[5]=(short)f2bf(s1.y); a[6]=(short)f2bf(s1.z); a[7]=(short)f2bf(s1.w);
      }
      #pragma unroll
      for (int ct = 0; ct < 8; ct++){
        int col = ct * 16 + rl;
        int byte = (col << 8) + (kk << 1);
        bfrag8 b = *(const bfrag8*)(lds + (byte ^ ((col & 7) << 4)));
        accF[ct] = __builtin_amdgcn_mfma_f32_16x16x32_bf16(a, b, accF[ct], 0, 0, 0);
      }
    }
  }
  __syncthreads();                               // f1-half0 reads done
  // stage fcs1 K-half 1 (fl part)
  {
    const char* src = (const char*)(f1T + (size_t)i * 32768) + 256;
    for (int c = threadIdx.x; c < 2048; c += 256){
      int n = c >> 4, off = (c & 15) << 4;
      *(bfrag8*)(lds + ((n * 256 + off) ^ ((n & 7) << 4))) =
          *(const bfrag8*)(src + (size_t)n * 512 + off);
    }
  }
  __syncthreads();
  // ---- Phase B2: fcs1, k in [128,256) — A = fl (act LDS) ----
  #pragma unroll
  for (int kc = 0; kc < 4; kc++){
    int kl = kc * 32 + kg * 8;
    int byteA = lr * 256 + kl * 2;
    bfrag8 a = *(const bfrag8*)(actL + (byteA ^ ((lr & 7) << 4)));
    #pragma unroll
    for (int ct = 0; ct < 8; ct++){
      int col = ct * 16 + rl;
      int byte = (col << 8) + (kl << 1);
      bfrag8 b = *(const bfrag8*)(lds + (byte ^ ((col & 7) << 4)));
      accF[ct] = __builtin_amdgcn_mfma_f32_16x16x32_bf16(a, b, accF[ct], 0, 0, 0);
    }
  }
  __syncthreads();                               // act(fl) + f1-half1 reads done
  // fc (+bias, kept f32 in accF) -> act LDS; stage fcs2 W
  {
    const float* bias = f1b + i * HID_;
    #pragma unroll
    for (int ct = 0; ct < 8; ct++){
      int col = ct * 16 + rl;
      float bv = bias[col];
      #pragma unroll
      for (int r = 0; r < 4; r++){
        int ar = wv * 16 + kg * 4 + r;
        float v = accF[ct][r] + bv;
        accF[ct][r] = v;
        int byte = ar * 256 + col * 2;
        *(unsigned short*)(actL + (byte ^ ((ar & 7) << 4))) = f2bf(v);
      }
    }
    const char* src = (const char*)(f2T + (size_t)i * 16384);
    for (int c = threadIdx.x; c < 2048; c += 256){
      int byte = c << 4; int n = byte >> 8;
      *(bfrag8*)(lds + (byte ^ ((n & 7) << 4))) = *(const bfrag8*)(src + byte);
    }
  }
  __syncthreads();
  // ---- Phase C: fcs2 + gate epilogue ----
  facc4 accT[8];
  #pragma unroll
  for (int ct = 0; ct < 8; ct++) accT[ct] = (facc4){0.f,0.f,0.f,0.f};
  #pragma unroll
  for (int kc = 0; kc < 4; kc++){
    int kk = kc * 32 + kg * 8;
    int byteA = lr * 256 + kk * 2;
    bfrag8 a = *(const bfrag8*)(actL + (byteA ^ ((lr & 7) << 4)));
    #pragma unroll
    for (int ct = 0; ct < 8; ct++){
      int col = ct * 16 + rl;
      int byte = (col << 8) + (kk << 1);
      bfrag8 b = *(const bfrag8*)(lds + (byte ^ ((col & 7) << 4)));
      accT[ct] = __builtin_amdgcn_mfma_f32_16x16x32_bf16(a, b, accT[ct], 0, 0, 0);
    }
  }
  {
    const float* bias2 = f2b + i * HID_;
    #pragma unroll
    for (int ct = 0; ct < 8; ct++){
      int col = ct * 16 + rl;
      float bv2 = bias2[col];
      #pragma unroll
      for (int r = 0; r < 4; r++){
        int orow = rowBase + kg * 4 + r;
        if (orow < BM_){
          float tv = accT[ct][r] + bv2;
          float fw = 1.f / (1.f + expf(-tv));
          float u = accF[ct][r] * fw;
          u = u > 0.f ? u : 0.f;
          seg[(size_t)orow * (NSC_ * HID_) + i * HID_ + col] = f2bf(u);
        }
      }
    }
  }
}

// Fused classifier: logits = relu(seg @ W1 + b1) @ W2 + b2.
// W1 staged as 4 x 32KB K-quarters; 48KB LDS, 3 blocks/CU.
__global__ __launch_bounds__(256, 3) void k_cls(const unsigned short* __restrict__ seg,
    const unsigned short* __restrict__ c1T, const float* __restrict__ c1b,
    const unsigned short* __restrict__ c2T, const float* __restrict__ c2b,
    float* __restrict__ logits){
  __shared__ char lds[49152];
  char* actL = lds + 32768;
  const int lane = threadIdx.x & 63, wv = threadIdx.x >> 6;
  const int rl = lane & 15, kg = lane >> 4;
  const int rowBase = blockIdx.x * 64 + wv * 16;
  const int row = rowBase + rl;
  const bool rv = row < BM_;
  const unsigned short* ar = seg + (size_t)(rv ? row : 0) * 512;
  facc4 acc[8];
  #pragma unroll
  for (int ct = 0; ct < 8; ct++) acc[ct] = (facc4){0.f,0.f,0.f,0.f};
  for (int ph = 0; ph < 4; ph++){
    if (ph) __syncthreads();
    for (int c = threadIdx.x; c < 2048; c += 256){
      int n = c >> 4, off = (c & 15) << 4;
      *(bfrag8*)(lds + ((n * 256 + off) ^ ((n & 7) << 4))) =
          *(const bfrag8*)((const char*)c1T + (size_t)n * 1024 + ph * 256 + off);
    }
    __syncthreads();
    #pragma unroll
    for (int kc = 0; kc < 4; kc++){
      int kl = kc * 32 + kg * 8;
      bfrag8 a = (bfrag8){0,0,0,0,0,0,0,0};
      if (rv) a = *(const bfrag8*)(ar + ph * 128 + kl);
      #pragma unroll
      for (int ct = 0; ct < 8; ct++){
        int col = ct * 16 + rl;
        int byte = (col << 8) + (kl << 1);
        bfrag8 b = *(const bfrag8*)(lds + (byte ^ ((col & 7) << 4)));
        acc[ct] = __builtin_amdgcn_mfma_f32_16x16x32_bf16(a, b, acc[ct], 0, 0, 0);
      }
    }
  }
  __syncthreads();
  // relu(hid) -> act LDS; stage W2 bf16 [20][128] (5120B at lds+0)
  #pragma unroll
  for (int ct = 0; ct < 8; ct++){
    int col = ct * 16 + rl;
    float bv = c1b[col];
    #pragma unroll
    for (int r = 0; r < 4; r++){
      int arr = wv * 16 + kg * 4 + r;
      float v = acc[ct][r] + bv; v = v > 0.f ? v : 0.f;
      int byte = arr * 256 + col * 2;
      *(unsigned short*)(actL + (byte ^ ((arr & 7) << 4))) = f2bf(v);
    }
  }
  for (int c = threadIdx.x; c < 320; c += 256)
    *(bfrag8*)(lds + (c << 4)) = *(const bfrag8*)((const char*)c2T + (c << 4));
  __syncthreads();
  // dot: thread -> (local row = t>>2, n-range = (t&3)*5 .. +5)
  {
    int t = threadIdx.x;
    int lrd = t >> 2, n0 = (t & 3) * 5;
    int orow = blockIdx.x * 64 + lrd;
    if (orow < BM_){
      float accD[5];
      #pragma unroll
      for (int q = 0; q < 5; q++) accD[q] = c2b[n0 + q];
      #pragma unroll
      for (int k8 = 0; k8 < 16; k8++){
        int byteA = lrd * 256 + (k8 << 4);
        bfrag8 hv = *(const bfrag8*)(actL + (byteA ^ ((lrd & 7) << 4)));
        #pragma unroll
        for (int q = 0; q < 5; q++){
          bfrag8 w8 = *(const bfrag8*)(lds + (n0 + q) * 256 + (k8 << 4));
          #pragma unroll
          for (int e = 0; e < 8; e++)
            accD[q] += bf2f((unsigned short)hv[e]) * bf2f((unsigned short)w8[e]);
        }
      }
      #pragma unroll
      for (int q = 0; q < 5; q++)
        logits[(size_t)orow * NCLS_ + n0 + q] = accD[q];
    }
  }
}

// ---------------------------------------------------------------------------
extern "C" void kernel_launch(void* const* d_in, const int* in_sizes, int n_in,
                              void* d_out, int out_size, void* d_ws, size_t ws_size,
                              hipStream_t stream){
  const float* samp = (const float*)d_in[1];   // pts_sample_feat (pts_feat_layers is dead)
  const float* img  = (const float*)d_in[2];
  const float* imgf = (const float*)d_in[3];
  const float* lW   = (const float*)d_in[4];
  const float* lb   = (const float*)d_in[5];
  const float* f1W  = (const float*)d_in[6];
  const float* f1b  = (const float*)d_in[7];
  const float* f2W  = (const float*)d_in[8];
  const float* f2b  = (const float*)d_in[9];
  const float* c1W  = (const float*)d_in[10];
  const float* c1b  = (const float*)d_in[11];
  const float* c2W  = (const float*)d_in[12];
  const float* c2b  = (const float*)d_in[13];
  const int* ptsimg = (const int*)d_in[14];
  const int* p2i    = (const int*)d_in[15];
  const int* si     = (const int*)d_in[16];
  const int* ci     = (const int*)d_in[17];

  char* ws = (char*)d_ws;
  int*   win_p = (int*)(ws + 0);                       //   960,000 B
  int*   win_s = (int*)(ws + 960000);                  //   960,000 B
  int*   win_c = (int*)(ws + 1920000);                 //   400,000 B
  unsigned short* iap = (unsigned short*)(ws + 2320128);    // 15,360,000 B
  unsigned short* seg = (unsigned short*)(ws + 17680384);   // 61,440,000 B
  unsigned short* lwT = (unsigned short*)(ws + 79120512);   // 131,072 B
  unsigned short* f1T = lwT + 65536;                        // 262,144 B
  unsigned short* f2T = f1T + 131072;                       // 131,072 B
  unsigned short* c1T = f2T + 65536;                        // 131,072 B
  unsigned short* c2T = c1T + 65536;                        //   5,120 B

  float* logits = (float*)d_out;
  float* o3d    = (float*)d_out + (size_t)BM_ * NCLS_;

  (void)hipMemsetAsync(ws, 0xFF, 2320000, stream);     // win_* = -1
  k_front  <<<9728,  256, 0, stream>>>(img, ptsimg, iap, p2i, si, ci,
                                       win_p, win_s, win_c,
                                       lW, f1W, f2W, c1W, c2W,
                                       lwT, f1T, f2T, c1T, c2T);
  k_o3d    <<<30000, 256, 0, stream>>>(samp, win_s, win_p, iap, o3d);
  k_scales <<<3752,  256, 0, stream>>>(samp, iap, win_p, win_s, win_c, p2i, ci,
                                       imgf, lwT, lb, f1T, f1b, f2T, f2b, seg);
  k_cls    <<<938,   256, 0, stream>>>(seg, c1T, c1b, c2T, c2b, logits);
}